// Round 3
// baseline (469.264 us; speedup 1.0000x reference)
//
#include <hip/hip_runtime.h>
#include <stdint.h>

#define NCK 21
// NOTE: reference computes K_EASY = int(200*(1-0.8)) = int(39.9999...) = 39 (Python float trunc!)
#define K_EASY 39
#define K_HARD 160
#define A_TOT  199
#define MARGINF 0.2f

// ws byte offsets
#define OFF_EASY   64
#define OFF_HARD   256
#define OFF_PERA   1024
#define OFF_FLAGS1 4096
#define OFF_FLAGS2 135168
#define OFF_ANCH   266240
#define OFF_SIMS   409600

__device__ __forceinline__ unsigned int f2key(float f) {
  unsigned int u = __float_as_uint(f);
  return u ^ ((u & 0x80000000u) ? 0xFFFFFFFFu : 0x80000000u);
}
__device__ __forceinline__ float key2f(unsigned int k) {
  unsigned int u = (k & 0x80000000u) ? (k ^ 0x80000000u) : (k ^ 0xFFFFFFFFu);
  return __uint_as_float(u);
}

// K0: init header
__global__ void k_init(int* hdr) {
  if (threadIdx.x == 0) hdr[0] = NCK;  // cls accumulator for atomicMin
}

// K1: downsampled label/fg byte per pixel + global min class
__global__ void k_prep(const int* __restrict__ wsss, const int* __restrict__ fsss,
                       unsigned char* __restrict__ flags1, int* __restrict__ hdr) {
  int p = blockIdx.x * 256 + threadIdx.x;           // 0..131071
  int b = p >> 14, r = p & 16383, i = r >> 7, j = r & 127;
  int gi = (b * 512 + i * 4) * 512 + j * 4;
  int w = wsss[gi];
  int f = fsss[gi];
  int fg = (f != 0 && f != 255) ? 1 : 0;
  int wl = (w != 0 && w != 255) ? 1 : 0;
  flags1[p] = (unsigned char)((w & 63) | (fg << 6));
  int cand = wl ? w : NCK;
  for (int off = 32; off > 0; off >>= 1) cand = min(cand, __shfl_down(cand, off));
  __shared__ int wmin[4];
  int lane = threadIdx.x & 63, wid = threadIdx.x >> 6;
  if (lane == 0) wmin[wid] = cand;
  __syncthreads();
  if (threadIdx.x == 0) {
    int m = min(min(wmin[0], wmin[1]), min(wmin[2], wmin[3]));
    atomicMin(&hdr[0], m);
  }
}

// K2: easy/hard flags (argmax over 21 channels only at candidate pixels)
__global__ void k_flags(const float* __restrict__ preds, const unsigned char* __restrict__ flags1,
                        unsigned char* __restrict__ flags2, const int* __restrict__ hdr) {
  int p = blockIdx.x * 256 + threadIdx.x;
  int cls = hdr[0];
  unsigned char f1 = flags1[p];
  unsigned char out = 0;
  if ((f1 & 64) && (int)(f1 & 63) == cls) {
    int b = p >> 14, r = p & 16383, i = r >> 7, j = r & 127;
    int base = ((b * NCK) * 512 + i * 4) * 512 + j * 4;
    float best = preds[base]; int bi = 0;
#pragma unroll
    for (int ch = 1; ch < NCK; ++ch) {
      float v = preds[base + ch * 262144];
      if (v > best) { best = v; bi = ch; }
    }
    out = (bi == cls) ? 1 : 2;
  }
  flags2[p] = out;
}

// K3: ordered selection of first 39 easy / 160 hard indices.
// Single wave (64 lanes): per-lane 8-byte counts, one shfl_up prefix scan,
// no shared memory, no barriers. Wave-uniform early exit once both caps hit.
__global__ void k_pick(const unsigned char* __restrict__ flags2, int* __restrict__ hdr,
                       int* __restrict__ easy_idx, int* __restrict__ hard_idx) {
  int lane = threadIdx.x;  // 0..63
  const unsigned long long* f8 = (const unsigned long long*)flags2;
  unsigned int runE = 0, runH = 0;
  for (int it = 0; it < 256; ++it) {      // 256 * 64 lanes * 8 bytes = 131072
    unsigned long long v = f8[it * 64 + lane];
    unsigned int e = 0, h = 0;
#pragma unroll
    for (int g = 0; g < 8; ++g) {
      unsigned int b = (unsigned int)((v >> (8 * g)) & 255ull);
      e += (b == 1u); h += (b == 2u);
    }
    unsigned int x = (e << 16) | h;       // per-lane <=8 each; wave sums <=512 fit 16b
    unsigned int incl = x;
#pragma unroll
    for (int off = 1; off < 64; off <<= 1) {
      unsigned int t = __shfl_up(incl, off);
      if (lane >= off) incl += t;
    }
    unsigned int excl = incl - x;
    unsigned int eRk = runE + (excl >> 16);
    unsigned int hRk = runH + (excl & 0xFFFFu);
#pragma unroll
    for (int g = 0; g < 8; ++g) {
      unsigned int b = (unsigned int)((v >> (8 * g)) & 255ull);
      int p = it * 512 + lane * 8 + g;
      if (b == 1u)      { if (eRk < K_EASY) easy_idx[eRk] = p; eRk++; }
      else if (b == 2u) { if (hRk < K_HARD) hard_idx[hRk] = p; hRk++; }
    }
    unsigned int tot = __shfl(incl, 63);  // wave total this iteration
    runE += (tot >> 16); runH += (tot & 0xFFFFu);
    if (runE >= K_EASY && runH >= K_HARD) break;   // uniform
  }
  if (lane == 0) {
    int neU = runE < K_EASY ? (int)runE : K_EASY;
    int nhU = runH < K_HARD ? (int)runH : K_HARD;
    hdr[1] = (int)runE; hdr[2] = (int)runH;
    hdr[3] = neU; hdr[4] = nhU; hdr[5] = neU + nhU;
  }
}

// K4: gather + normalize anchor embeddings (pad to 256 rows with zeros)
__global__ void k_anchors(const float* __restrict__ emb, const int* __restrict__ hdr,
                          const int* __restrict__ easy_idx, const int* __restrict__ hard_idx,
                          float* __restrict__ anchors) {
  int a = blockIdx.x;        // 0..255
  int tid = threadIdx.x;     // 64
  int nv = hdr[5], neU = hdr[3];
  float v0 = 0.f, v1 = 0.f;
  if (a < nv) {
    int p = (a < neU) ? easy_idx[a] : hard_idx[a - neU];
    int b = p >> 14, r = p & 16383, i = r >> 7, j = r & 127;
    int base = b * 2097152 + i * 128 + j;
    v0 = emb[base + tid * 16384];
    v1 = emb[base + (tid + 64) * 16384];
  }
  float ss = v0 * v0 + v1 * v1;
  for (int off = 32; off > 0; off >>= 1) ss += __shfl_xor(ss, off);
  float inv = 1.0f / fmaxf(sqrtf(ss), 1e-12f);
  anchors[a * 128 + tid] = v0 * inv;
  anchors[a * 128 + tid + 64] = v1 * inv;
}

// K5: sims[la][cm] = dot(anchor_{a0+la}, mem_row_cm) * invnorm(mem_row).
// 64x64 tiles, fp32. Anchor dimension chunked by host to fit ws_size.
__global__ __launch_bounds__(256) void k_sims(const float* __restrict__ anchors,
                       const float* __restrict__ memory, float* __restrict__ sims,
                       int a0, int ac) {
  __shared__ float As[64 * 128];
  __shared__ float Ms[64 * 128];
  int mT = blockIdx.x, aT = blockIdx.y;
  int aBase = aT * 64, mBase = mT * 64;
  int tid = threadIdx.x;
#pragma unroll
  for (int k = 0; k < 8; ++k) {   // stage A (swizzled 16B chunks)
    int f4i = tid + k * 256;
    int row = f4i >> 5, c = f4i & 31;
    int gR = a0 + aBase + row; if (gR > 255) gR = 255;   // clamp: stay in anchors buf
    float4 v = ((const float4*)anchors)[gR * 32 + c];
    *(float4*)&As[row * 128 + ((c ^ (row & 31)) << 2)] = v;
  }
#pragma unroll
  for (int k = 0; k < 8; ++k) {   // stage M
    int f4i = tid + k * 256;
    int row = f4i >> 5, c = f4i & 31;
    int grow = mBase + row;
    float4 v = make_float4(0.f, 0.f, 0.f, 0.f);
    if (grow < 20000) v = ((const float4*)memory)[grow * 32 + c];
    *(float4*)&Ms[row * 128 + ((c ^ (row & 31)) << 2)] = v;
  }
  __syncthreads();
  int tx = tid & 15, ty = tid >> 4;   // micro-tile rows: a = ty+16i, m = tx+16j
  float acc[4][4];
#pragma unroll
  for (int i = 0; i < 4; ++i)
#pragma unroll
    for (int j = 0; j < 4; ++j) acc[i][j] = 0.f;
#pragma unroll 2
  for (int c = 0; c < 32; ++c) {
    float4 av[4], mv[4];
#pragma unroll
    for (int i = 0; i < 4; ++i) {
      int ar = ty + 16 * i;
      av[i] = *(const float4*)&As[ar * 128 + ((c ^ (ar & 31)) << 2)];
    }
#pragma unroll
    for (int j = 0; j < 4; ++j) {
      int mr = tx + 16 * j;
      mv[j] = *(const float4*)&Ms[mr * 128 + ((c ^ (mr & 31)) << 2)];
    }
#pragma unroll
    for (int i = 0; i < 4; ++i)
#pragma unroll
      for (int j = 0; j < 4; ++j)
        acc[i][j] += av[i].x * mv[j].x + av[i].y * mv[j].y + av[i].z * mv[j].z + av[i].w * mv[j].w;
  }
  __syncthreads();
  {  // memory-row inverse norms into As[0..63] (row content is a per-row permutation: sum identical)
    int row = tid >> 2, q = tid & 3;
    float ss = 0.f;
#pragma unroll
    for (int k = 0; k < 8; ++k) {
      float4 v = *(const float4*)&Ms[row * 128 + q * 32 + k * 4];
      ss += v.x * v.x + v.y * v.y + v.z * v.z + v.w * v.w;
    }
    ss += __shfl_down(ss, 2, 4);
    ss += __shfl_down(ss, 1, 4);
    if (q == 0) As[row] = 1.0f / fmaxf(sqrtf(ss), 1e-8f);
  }
  __syncthreads();
#pragma unroll
  for (int i = 0; i < 4; ++i) {
    int la = aBase + ty + 16 * i;           // chunk-local anchor row
    if (la < ac) {
#pragma unroll
      for (int j = 0; j < 4; ++j) {
        int m = mBase + tx + 16 * j;
        if (m < 20000) sims[(size_t)la * 20000 + m] = acc[i][j] * As[tx + 16 * j];
      }
    }
  }
}

// K6: per-anchor exact top-1000 negatives threshold + pair-loss sum
__global__ __launch_bounds__(256) void k_topk(const float* __restrict__ sims,
                       const int* __restrict__ hdr, float* __restrict__ per_anchor,
                       int a0, int ac) {
  int la = blockIdx.x;
  if (la >= ac) return;
  int a = a0 + la;
  int nv = hdr[5];
  if (a >= nv) return;
  int cls = hdr[0];
  int clsRow = cls - 1;
  int tid = threadIdx.x, lane = tid & 63, wid = tid >> 6;
  __shared__ float posArr[1024];
  __shared__ unsigned int hist[4][256];
  __shared__ unsigned int buf[12288];
  __shared__ float qv[1024];
  __shared__ unsigned int sred[4];
  __shared__ unsigned int scounts[4];
  __shared__ float fred[4];
  const float* row = sims + (size_t)la * 20000;

  // Phase A: stash pos row, 8-bit key histogram of negatives
#pragma unroll
  for (int k = 0; k < 4; ++k) ((unsigned int*)hist)[tid + k * 256] = 0u;
  if (tid < 24) posArr[1000 + tid] = -1e30f;
  __syncthreads();
  for (int j = tid; j < 20000; j += 256) {
    float v = row[j];
    int c = j / 1000;
    if (c == clsRow) posArr[j - clsRow * 1000] = v;
    else atomicAdd(&hist[wid][f2key(v) >> 24], 1u);
  }
  __syncthreads();
  { unsigned int s = hist[0][tid] + hist[1][tid] + hist[2][tid] + hist[3][tid]; hist[0][tid] = s; }
  __syncthreads();
  if (tid == 0) {
    int krem = 1000; int b = 255;
    for (; b > 0; --b) {
      unsigned int h = hist[0][b];
      if ((unsigned int)krem <= h) break;
      krem -= (int)h;
    }
    scounts[0] = (unsigned int)b;
    scounts[1] = (unsigned int)krem;
    scounts[2] = 0u;
  }
  __syncthreads();
  unsigned int B0 = scounts[0];
  int krem = (int)scounts[1];

  // Phase B: compact keys whose top byte == B0
  for (int j = tid; j < 20000; j += 256) {
    float v = row[j];
    int c = j / 1000;
    unsigned int key = f2key(v);
    bool pred = (c != clsRow) && ((key >> 24) == B0);
    unsigned long long mask = __ballot(pred);
    unsigned int base = 0u;
    if (lane == 0) base = mask ? atomicAdd(&scounts[2], (unsigned int)__popcll(mask)) : 0u;
    base = __shfl(base, 0);
    if (pred) {
      unsigned int pos = base + (unsigned int)__popcll(mask & ((1ull << lane) - 1ull));
      if (pos < 12288u) buf[pos] = key;
    }
  }
  __syncthreads();
  int n2 = (int)scounts[2];

  // Phase C: 24-round 1-bit radix descend for exact 1000th-largest key
  unsigned int prefix = B0 << 24;
  for (int bit = 23; bit >= 0; --bit) {
    unsigned int hiMask = 0xFFFFFFFFu << (bit + 1);
    unsigned int bmask = 1u << bit;
    int c1 = 0;
    if (n2 <= 12288) {
      for (int j2 = tid; j2 < n2; j2 += 256) {
        unsigned int k = buf[j2];
        if ((k & hiMask) == prefix && (k & bmask)) c1++;
      }
    } else {  // fallback: rescan global (correctness insurance; ~never taken)
      for (int j = tid; j < 20000; j += 256) {
        int c = j / 1000;
        if (c != clsRow) {
          unsigned int k = f2key(row[j]);
          if ((k & hiMask) == prefix && (k & bmask)) c1++;
        }
      }
    }
    for (int off = 32; off; off >>= 1) c1 += __shfl_down(c1, off);
    __syncthreads();
    if (lane == 0) sred[wid] = (unsigned int)c1;
    __syncthreads();
    c1 = (int)(sred[0] + sred[1] + sred[2] + sred[3]);
    if (c1 >= krem) prefix |= bmask;
    else krem -= c1;
  }
  float tval = key2f(prefix);

  // Phase D: compact strictly-greater negative values
  if (tid == 0) scounts[3] = 0u;
  __syncthreads();
  for (int j = tid; j < 20000; j += 256) {
    float v = row[j];
    int c = j / 1000;
    unsigned int key = f2key(v);
    bool pred = (c != clsRow) && (key > prefix);
    unsigned long long mask = __ballot(pred);
    unsigned int base = 0u;
    if (lane == 0) base = mask ? atomicAdd(&scounts[3], (unsigned int)__popcll(mask)) : 0u;
    base = __shfl(base, 0);
    if (pred) qv[base + (unsigned int)__popcll(mask & ((1ull << lane) - 1ull))] = v;
  }
  __syncthreads();
  int qn = (int)scounts[3];             // count_gt <= 999
  float tieW = (float)(1000 - qn);      // copies of tval in the top-1000 multiset

  // Phase E: sum over top-1000 negs x 1000 pos of relu(pos - neg + margin)
  float local = 0.f;
  for (int pc = 0; pc < 1024; pc += 32) {
    float pvm[32];
#pragma unroll
    for (int k = 0; k < 8; ++k) {
      float4 t4 = *(const float4*)&posArr[pc + k * 4];
      pvm[k * 4 + 0] = t4.x + MARGINF; pvm[k * 4 + 1] = t4.y + MARGINF;
      pvm[k * 4 + 2] = t4.z + MARGINF; pvm[k * 4 + 3] = t4.w + MARGINF;
    }
    for (int e = tid; e <= qn; e += 256) {
      float v = (e < qn) ? qv[e] : tval;
      float w = (e < qn) ? 1.f : tieW;
      float s = 0.f;
#pragma unroll
      for (int k = 0; k < 32; ++k) s += fmaxf(pvm[k] - v, 0.f);
      local += w * s;
    }
  }
  for (int off = 32; off; off >>= 1) local += __shfl_down(local, off);
  __syncthreads();
  if (lane == 0) fred[wid] = local;
  __syncthreads();
  if (tid == 0) per_anchor[a] = (fred[0] + fred[1] + fred[2] + fred[3]) * 1e-6f;
}

// K7: loss reduce
__global__ void k_loss(const float* __restrict__ per_anchor, const int* __restrict__ hdr,
                       float* __restrict__ out) {
  int nv = hdr[5];
  int tid = threadIdx.x;
  float s = (tid < nv) ? per_anchor[tid] : 0.f;
  for (int off = 32; off; off >>= 1) s += __shfl_down(s, off);
  __shared__ float fr[4];
  if ((tid & 63) == 0) fr[tid >> 6] = s;
  __syncthreads();
  if (tid == 0) out[0] = (fr[0] + fr[1] + fr[2] + fr[3]) / (float)max(nv, 1);
}

// K8: new_memory = memory with row cls-1 slots [0,nv) replaced by anchors
__global__ void k_writemem(const float* __restrict__ memory, const float* __restrict__ anchors,
                           const int* __restrict__ hdr, float* __restrict__ out) {
  int cls = hdr[0], nv = hdr[5];
  int i = blockIdx.x * 1024 + threadIdx.x;
#pragma unroll
  for (int k = 0; k < 4; ++k, i += 256) {
    float v = memory[i];
    int c = i / 128000;
    int rem = i - c * 128000;
    int m = rem >> 7, d = rem & 127;
    if (cls >= 1 && cls <= 20 && c == cls - 1 && m < nv) v = anchors[m * 128 + d];
    out[1 + i] = v;
  }
}

extern "C" void kernel_launch(void* const* d_in, const int* in_sizes, int n_in,
                              void* d_out, int out_size, void* d_ws, size_t ws_size,
                              hipStream_t stream) {
  const float* preds  = (const float*)d_in[0];
  const float* emb    = (const float*)d_in[1];
  const int*   wsss   = (const int*)d_in[2];
  const int*   fsss   = (const int*)d_in[3];
  const float* memory = (const float*)d_in[4];
  float* out = (float*)d_out;
  char* ws = (char*)d_ws;
  int* hdr = (int*)ws;
  int* easy_idx = (int*)(ws + OFF_EASY);
  int* hard_idx = (int*)(ws + OFF_HARD);
  float* per_anchor = (float*)(ws + OFF_PERA);
  unsigned char* flags1 = (unsigned char*)(ws + OFF_FLAGS1);
  unsigned char* flags2 = (unsigned char*)(ws + OFF_FLAGS2);
  float* anchors = (float*)(ws + OFF_ANCH);
  float* sims = (float*)(ws + OFF_SIMS);

  hipLaunchKernelGGL(k_init,    dim3(1),   dim3(64),  0, stream, hdr);
  hipLaunchKernelGGL(k_prep,    dim3(512), dim3(256), 0, stream, wsss, fsss, flags1, hdr);
  hipLaunchKernelGGL(k_flags,   dim3(512), dim3(256), 0, stream, preds, flags1, flags2, hdr);
  hipLaunchKernelGGL(k_pick,    dim3(1),   dim3(64),  0, stream, flags2, hdr, easy_idx, hard_idx);
  hipLaunchKernelGGL(k_anchors, dim3(256), dim3(64),  0, stream, emb, hdr, easy_idx, hard_idx, anchors);

  // Anchor-chunked sims+topk so the 199x20000 fp32 sims matrix never exceeds ws_size.
  long long avail = (long long)ws_size - (long long)OFF_SIMS;
  int chunkA = (avail > 0) ? (int)(avail / 80000LL) : 1;   // 20000*4 bytes per anchor row
  if (chunkA > A_TOT) chunkA = A_TOT;
  if (chunkA < 1) chunkA = 1;
  for (int aoff = 0; aoff < A_TOT; aoff += chunkA) {
    int acount = (A_TOT - aoff < chunkA) ? (A_TOT - aoff) : chunkA;
    dim3 gs(313, (acount + 63) / 64);
    hipLaunchKernelGGL(k_sims, gs, dim3(256), 0, stream, anchors, memory, sims, aoff, acount);
    hipLaunchKernelGGL(k_topk, dim3(acount), dim3(256), 0, stream, sims, hdr, per_anchor, aoff, acount);
  }

  hipLaunchKernelGGL(k_loss,    dim3(1),    dim3(256), 0, stream, per_anchor, hdr, out);
  hipLaunchKernelGGL(k_writemem,dim3(2500), dim3(256), 0, stream, memory, anchors, hdr, out);
}

// Round 4
// 385.158 us; speedup vs baseline: 1.2184x; 1.2184x over previous
//
#include <hip/hip_runtime.h>
#include <stdint.h>

#define NCK 21
// reference: K_EASY = int(200*(1-0.8)) = int(39.9999...) = 39 (Python float trunc!)
#define K_EASY 39
#define K_HARD 160
#define A_TOT  199
#define MARGINF 0.2f

// ws byte offsets
#define OFF_EASY   64
#define OFF_HARD   256
#define OFF_PERA   1024
#define OFF_FLAGS1 4096
#define OFF_FLAGS2 135168
#define OFF_ANCH   266240
#define OFF_SIMS   409600

__device__ __forceinline__ unsigned int f2key(float f) {
  unsigned int u = __float_as_uint(f);
  return u ^ ((u & 0x80000000u) ? 0xFFFFFFFFu : 0x80000000u);
}
__device__ __forceinline__ float key2f(unsigned int k) {
  unsigned int u = (k & 0x80000000u) ? (k ^ 0x80000000u) : (k ^ 0xFFFFFFFFu);
  return __uint_as_float(u);
}

// K0: init header
__global__ void k_init(int* hdr) {
  if (threadIdx.x == 0) hdr[0] = NCK;  // cls accumulator for atomicMin
}

// K1: downsampled label/fg byte per pixel + global min class
__global__ void k_prep(const int* __restrict__ wsss, const int* __restrict__ fsss,
                       unsigned char* __restrict__ flags1, int* __restrict__ hdr) {
  int p = blockIdx.x * 256 + threadIdx.x;           // 0..131071
  int b = p >> 14, r = p & 16383, i = r >> 7, j = r & 127;
  int gi = (b * 512 + i * 4) * 512 + j * 4;
  int w = wsss[gi];
  int f = fsss[gi];
  int fg = (f != 0 && f != 255) ? 1 : 0;
  int wl = (w != 0 && w != 255) ? 1 : 0;
  flags1[p] = (unsigned char)((w & 63) | (fg << 6));
  int cand = wl ? w : NCK;
  for (int off = 32; off > 0; off >>= 1) cand = min(cand, __shfl_down(cand, off));
  __shared__ int wmin[4];
  int lane = threadIdx.x & 63, wid = threadIdx.x >> 6;
  if (lane == 0) wmin[wid] = cand;
  __syncthreads();
  if (threadIdx.x == 0) {
    int m = min(min(wmin[0], wmin[1]), min(wmin[2], wmin[3]));
    atomicMin(&hdr[0], m);
  }
}

// K2: easy/hard flags (argmax over 21 channels only at candidate pixels)
__global__ void k_flags(const float* __restrict__ preds, const unsigned char* __restrict__ flags1,
                        unsigned char* __restrict__ flags2, const int* __restrict__ hdr) {
  int p = blockIdx.x * 256 + threadIdx.x;
  int cls = hdr[0];
  unsigned char f1 = flags1[p];
  unsigned char out = 0;
  if ((f1 & 64) && (int)(f1 & 63) == cls) {
    int b = p >> 14, r = p & 16383, i = r >> 7, j = r & 127;
    int base = ((b * NCK) * 512 + i * 4) * 512 + j * 4;
    float best = preds[base]; int bi = 0;
#pragma unroll
    for (int ch = 1; ch < NCK; ++ch) {
      float v = preds[base + ch * 262144];
      if (v > best) { best = v; bi = ch; }
    }
    out = (bi == cls) ? 1 : 2;
  }
  flags2[p] = out;
}

// K3: ordered selection of first 39 easy / 160 hard indices (single wave).
__global__ void k_pick(const unsigned char* __restrict__ flags2, int* __restrict__ hdr,
                       int* __restrict__ easy_idx, int* __restrict__ hard_idx) {
  int lane = threadIdx.x;  // 0..63
  const unsigned long long* f8 = (const unsigned long long*)flags2;
  unsigned int runE = 0, runH = 0;
  for (int it = 0; it < 256; ++it) {      // 256 * 64 lanes * 8 bytes = 131072
    unsigned long long v = f8[it * 64 + lane];
    unsigned int e = 0, h = 0;
#pragma unroll
    for (int g = 0; g < 8; ++g) {
      unsigned int b = (unsigned int)((v >> (8 * g)) & 255ull);
      e += (b == 1u); h += (b == 2u);
    }
    unsigned int x = (e << 16) | h;
    unsigned int incl = x;
#pragma unroll
    for (int off = 1; off < 64; off <<= 1) {
      unsigned int t = __shfl_up(incl, off);
      if (lane >= off) incl += t;
    }
    unsigned int excl = incl - x;
    unsigned int eRk = runE + (excl >> 16);
    unsigned int hRk = runH + (excl & 0xFFFFu);
#pragma unroll
    for (int g = 0; g < 8; ++g) {
      unsigned int b = (unsigned int)((v >> (8 * g)) & 255ull);
      int p = it * 512 + lane * 8 + g;
      if (b == 1u)      { if (eRk < K_EASY) easy_idx[eRk] = p; eRk++; }
      else if (b == 2u) { if (hRk < K_HARD) hard_idx[hRk] = p; hRk++; }
    }
    unsigned int tot = __shfl(incl, 63);
    runE += (tot >> 16); runH += (tot & 0xFFFFu);
    if (runE >= K_EASY && runH >= K_HARD) break;   // uniform
  }
  if (lane == 0) {
    int neU = runE < K_EASY ? (int)runE : K_EASY;
    int nhU = runH < K_HARD ? (int)runH : K_HARD;
    hdr[1] = (int)runE; hdr[2] = (int)runH;
    hdr[3] = neU; hdr[4] = nhU; hdr[5] = neU + nhU;
  }
}

// K4: gather + normalize anchor embeddings (pad to 256 rows with zeros)
__global__ void k_anchors(const float* __restrict__ emb, const int* __restrict__ hdr,
                          const int* __restrict__ easy_idx, const int* __restrict__ hard_idx,
                          float* __restrict__ anchors) {
  int a = blockIdx.x;        // 0..255
  int tid = threadIdx.x;     // 64
  int nv = hdr[5], neU = hdr[3];
  float v0 = 0.f, v1 = 0.f;
  if (a < nv) {
    int p = (a < neU) ? easy_idx[a] : hard_idx[a - neU];
    int b = p >> 14, r = p & 16383, i = r >> 7, j = r & 127;
    int base = b * 2097152 + i * 128 + j;
    v0 = emb[base + tid * 16384];
    v1 = emb[base + (tid + 64) * 16384];
  }
  float ss = v0 * v0 + v1 * v1;
  for (int off = 32; off > 0; off >>= 1) ss += __shfl_xor(ss, off);
  float inv = 1.0f / fmaxf(sqrtf(ss), 1e-12f);
  anchors[a * 128 + tid] = v0 * inv;
  anchors[a * 128 + tid + 64] = v1 * inv;
}

// K5: sims[la][cm] = dot(anchor_{a0+la}, mem_row_cm) * invnorm(mem_row). 64x64 tiles.
__global__ __launch_bounds__(256) void k_sims(const float* __restrict__ anchors,
                       const float* __restrict__ memory, float* __restrict__ sims,
                       int a0, int ac) {
  __shared__ float As[64 * 128];
  __shared__ float Ms[64 * 128];
  int mT = blockIdx.x, aT = blockIdx.y;
  int aBase = aT * 64, mBase = mT * 64;
  int tid = threadIdx.x;
#pragma unroll
  for (int k = 0; k < 8; ++k) {   // stage A (swizzled 16B chunks)
    int f4i = tid + k * 256;
    int row = f4i >> 5, c = f4i & 31;
    int gR = a0 + aBase + row; if (gR > 255) gR = 255;
    float4 v = ((const float4*)anchors)[gR * 32 + c];
    *(float4*)&As[row * 128 + ((c ^ (row & 31)) << 2)] = v;
  }
#pragma unroll
  for (int k = 0; k < 8; ++k) {   // stage M
    int f4i = tid + k * 256;
    int row = f4i >> 5, c = f4i & 31;
    int grow = mBase + row;
    float4 v = make_float4(0.f, 0.f, 0.f, 0.f);
    if (grow < 20000) v = ((const float4*)memory)[grow * 32 + c];
    *(float4*)&Ms[row * 128 + ((c ^ (row & 31)) << 2)] = v;
  }
  __syncthreads();
  int tx = tid & 15, ty = tid >> 4;
  float acc[4][4];
#pragma unroll
  for (int i = 0; i < 4; ++i)
#pragma unroll
    for (int j = 0; j < 4; ++j) acc[i][j] = 0.f;
#pragma unroll 2
  for (int c = 0; c < 32; ++c) {
    float4 av[4], mv[4];
#pragma unroll
    for (int i = 0; i < 4; ++i) {
      int ar = ty + 16 * i;
      av[i] = *(const float4*)&As[ar * 128 + ((c ^ (ar & 31)) << 2)];
    }
#pragma unroll
    for (int j = 0; j < 4; ++j) {
      int mr = tx + 16 * j;
      mv[j] = *(const float4*)&Ms[mr * 128 + ((c ^ (mr & 31)) << 2)];
    }
#pragma unroll
    for (int i = 0; i < 4; ++i)
#pragma unroll
      for (int j = 0; j < 4; ++j)
        acc[i][j] += av[i].x * mv[j].x + av[i].y * mv[j].y + av[i].z * mv[j].z + av[i].w * mv[j].w;
  }
  __syncthreads();
  {
    int row = tid >> 2, q = tid & 3;
    float ss = 0.f;
#pragma unroll
    for (int k = 0; k < 8; ++k) {
      float4 v = *(const float4*)&Ms[row * 128 + q * 32 + k * 4];
      ss += v.x * v.x + v.y * v.y + v.z * v.z + v.w * v.w;
    }
    ss += __shfl_down(ss, 2, 4);
    ss += __shfl_down(ss, 1, 4);
    if (q == 0) As[row] = 1.0f / fmaxf(sqrtf(ss), 1e-8f);
  }
  __syncthreads();
#pragma unroll
  for (int i = 0; i < 4; ++i) {
    int la = aBase + ty + 16 * i;
    if (la < ac) {
#pragma unroll
      for (int j = 0; j < 4; ++j) {
        int m = mBase + tx + 16 * j;
        if (m < 20000) sims[(size_t)la * 20000 + m] = acc[i][j] * As[tx + 16 * j];
      }
    }
  }
}

// 256-bin suffix-sum + boundary select: finds b = max{b: sum_{>=b} hist >= krem}.
// Result bucket in cnts[3]; sfx[] holds suffix sums (sfx[256]=0). All 1024 threads call.
__device__ __forceinline__ void suffix_select(unsigned int* histL, unsigned int* sfx,
                                              unsigned int* cnts, int tid, unsigned int krem) {
  if (tid < 256) sfx[tid] = histL[tid];
  if (tid == 256) sfx[256] = 0u;
  __syncthreads();
  for (int off = 1; off < 256; off <<= 1) {
    unsigned int add = 0u;
    if (tid < 256 && tid + off < 256) add = sfx[tid + off];
    __syncthreads();
    if (tid < 256) sfx[tid] += add;
    __syncthreads();
  }
  if (tid < 256) {
    unsigned int here = sfx[tid], next = sfx[tid + 1];
    if (here >= krem && next < krem) cnts[3] = (unsigned int)tid;
  }
  __syncthreads();
}

// K6: per-anchor exact top-1000 negatives + pair-loss. 1024 threads (16 waves).
__global__ __launch_bounds__(1024) void k_topk(const float* __restrict__ sims,
                       const int* __restrict__ hdr, float* __restrict__ per_anchor,
                       int a0, int ac) {
  int la = blockIdx.x;
  if (la >= ac) return;
  int a = a0 + la;
  int nv = hdr[5];
  if (a >= nv) return;
  int clsRow = hdr[0] - 1;
  int tid = threadIdx.x, lane = tid & 63, wid = tid >> 6;

  __shared__ float posArr[1024];
  __shared__ float qv[1024];
  __shared__ unsigned int hist16[16][256];
  __shared__ unsigned int histL[256];
  __shared__ unsigned int sfx[257];
  __shared__ unsigned int buf[12288];
  __shared__ unsigned int cnts[8];  // 1:bufCnt 2:qvCnt 3:sel 4:levelBufCnt
  __shared__ float fred[16];

  const float* row = sims + (size_t)la * 20000;

  // init
  for (int i = tid; i < 16 * 256; i += 1024) ((unsigned int*)hist16)[i] = 0u;
  if (tid < 24) posArr[1000 + tid] = -1e30f;
  if (tid < 8) cnts[tid] = 0u;
  __syncthreads();

  // P1: per-wave 256-bin histograms of neg keys' top byte; stash pos row
  for (int j = tid; j < 20000; j += 1024) {
    float v = row[j];
    int c = j / 1000;
    if (c == clsRow) posArr[j - clsRow * 1000] = v;
    else atomicAdd(&hist16[wid][f2key(v) >> 24], 1u);
  }
  __syncthreads();
  if (tid < 256) {
    unsigned int s = 0;
#pragma unroll
    for (int w = 0; w < 16; ++w) s += hist16[w][tid];
    histL[tid] = s;
  }
  __syncthreads();
  suffix_select(histL, sfx, cnts, tid, 1000u);
  unsigned int B0 = cnts[3];
  unsigned int krem = 1000u - sfx[B0 + 1];   // slots to fill from bucket B0
  __syncthreads();

  // P2: compact. top-byte > B0 -> qv (definitely top-1000); == B0 -> key buf
  for (int j = tid; j < 20000; j += 1024) {
    float v = row[j];
    int c = j / 1000;
    unsigned int key = f2key(v);
    unsigned int tb = key >> 24;
    bool pq = (c != clsRow) && (tb > B0);
    bool pb = (c != clsRow) && (tb == B0);
    unsigned long long mq = __ballot(pq);
    unsigned long long mb = __ballot(pb);
    unsigned int baseq = 0u, baseb = 0u;
    if (lane == 0) {
      if (mq) baseq = atomicAdd(&cnts[2], (unsigned int)__popcll(mq));
      if (mb) baseb = atomicAdd(&cnts[1], (unsigned int)__popcll(mb));
    }
    baseq = __shfl(baseq, 0); baseb = __shfl(baseb, 0);
    if (pq) qv[baseq + (unsigned int)__popcll(mq & ((1ull << lane) - 1ull))] = v;
    if (pb) {
      unsigned int p = baseb + (unsigned int)__popcll(mb & ((1ull << lane) - 1ull));
      if (p < 12288u) buf[p] = key;
    }
  }
  __syncthreads();
  int ncand = (int)cnts[1];
  bool stored = (ncand <= 12288);

  // P3: three byte-level radix passes for exact threshold key
  unsigned int prefix = B0 << 24;
  for (int level = 0; level < 3; ++level) {
    int shift = 16 - level * 8;
    if (tid < 256) histL[tid] = 0u;
    __syncthreads();
    unsigned int myk[12]; int myc = 0;
    if (stored) {
      for (int i = tid; i < ncand; i += 1024) myk[myc++] = buf[i];
      __syncthreads();   // all reads done before buf rewrite
      for (int k = 0; k < myc; ++k) atomicAdd(&histL[(myk[k] >> shift) & 255u], 1u);
    } else {
      unsigned int hiMask = 0xFFFFFFFFu << (shift + 8);
      for (int j = tid; j < 20000; j += 1024) {
        int c = j / 1000;
        if (c == clsRow) continue;
        unsigned int key = f2key(row[j]);
        if ((key & hiMask) == prefix) atomicAdd(&histL[(key >> shift) & 255u], 1u);
      }
    }
    __syncthreads();
    suffix_select(histL, sfx, cnts, tid, krem);
    unsigned int bk = cnts[3];
    unsigned int above = sfx[bk + 1];
    krem -= above;
    prefix |= bk << shift;
    if (stored) {
      __syncthreads();
      if (tid == 0) cnts[4] = 0u;
      __syncthreads();
      for (int k = 0; k < myc; ++k) {
        unsigned int b = (myk[k] >> shift) & 255u;
        if (b > bk) qv[atomicAdd(&cnts[2], 1u)] = key2f(myk[k]);
        else if (b == bk) buf[atomicAdd(&cnts[4], 1u)] = myk[k];
      }
      __syncthreads();
      ncand = (int)cnts[4];
    }
  }
  float tval = key2f(prefix);

  if (!stored) {   // fallback: gather all > threshold within bucket B0 from global
    for (int j = tid; j < 20000; j += 1024) {
      int c = j / 1000;
      if (c == clsRow) continue;
      float v = row[j];
      unsigned int key = f2key(v);
      if ((key >> 24) == B0 && key > prefix) qv[atomicAdd(&cnts[2], 1u) & 1023u] = v;
    }
    __syncthreads();
  }
  int qn = (int)cnts[2];          // strictly-greater count, <= 999
  float tieW = (float)krem;       // == 1000 - qn copies of tval

  // P4: one negative per thread; sum relu(pos + margin - neg) over 1024-padded pos
  float v, w;
  if (tid < qn)       { v = qv[tid]; w = 1.f; }
  else if (tid == qn) { v = tval;    w = tieW; }
  else                { v = 0.f;     w = 0.f; }
  float t = v - MARGINF;
  float s0 = 0.f, s1 = 0.f, s2 = 0.f, s3 = 0.f;
  if (w != 0.f) {
    for (int pc = 0; pc < 1024; pc += 16) {
      float4 p0 = *(const float4*)&posArr[pc];
      float4 p1 = *(const float4*)&posArr[pc + 4];
      float4 p2 = *(const float4*)&posArr[pc + 8];
      float4 p3 = *(const float4*)&posArr[pc + 12];
      s0 += fmaxf(p0.x - t, 0.f); s1 += fmaxf(p0.y - t, 0.f);
      s2 += fmaxf(p0.z - t, 0.f); s3 += fmaxf(p0.w - t, 0.f);
      s0 += fmaxf(p1.x - t, 0.f); s1 += fmaxf(p1.y - t, 0.f);
      s2 += fmaxf(p1.z - t, 0.f); s3 += fmaxf(p1.w - t, 0.f);
      s0 += fmaxf(p2.x - t, 0.f); s1 += fmaxf(p2.y - t, 0.f);
      s2 += fmaxf(p2.z - t, 0.f); s3 += fmaxf(p2.w - t, 0.f);
      s0 += fmaxf(p3.x - t, 0.f); s1 += fmaxf(p3.y - t, 0.f);
      s2 += fmaxf(p3.z - t, 0.f); s3 += fmaxf(p3.w - t, 0.f);
    }
  }
  float local = w * ((s0 + s1) + (s2 + s3));
  for (int off = 32; off; off >>= 1) local += __shfl_down(local, off);
  if (lane == 0) fred[wid] = local;
  __syncthreads();
  if (tid == 0) {
    float s = 0.f;
#pragma unroll
    for (int i = 0; i < 16; ++i) s += fred[i];
    per_anchor[a] = s * 1e-6f;
  }
}

// K7: loss reduce
__global__ void k_loss(const float* __restrict__ per_anchor, const int* __restrict__ hdr,
                       float* __restrict__ out) {
  int nv = hdr[5];
  int tid = threadIdx.x;
  float s = (tid < nv) ? per_anchor[tid] : 0.f;
  for (int off = 32; off; off >>= 1) s += __shfl_down(s, off);
  __shared__ float fr[4];
  if ((tid & 63) == 0) fr[tid >> 6] = s;
  __syncthreads();
  if (tid == 0) out[0] = (fr[0] + fr[1] + fr[2] + fr[3]) / (float)max(nv, 1);
}

// K8: new_memory = memory with row cls-1 slots [0,nv) replaced by anchors
__global__ void k_writemem(const float* __restrict__ memory, const float* __restrict__ anchors,
                           const int* __restrict__ hdr, float* __restrict__ out) {
  int cls = hdr[0], nv = hdr[5];
  int i = blockIdx.x * 1024 + threadIdx.x;
#pragma unroll
  for (int k = 0; k < 4; ++k, i += 256) {
    float v = memory[i];
    int c = i / 128000;
    int rem = i - c * 128000;
    int m = rem >> 7, d = rem & 127;
    if (cls >= 1 && cls <= 20 && c == cls - 1 && m < nv) v = anchors[m * 128 + d];
    out[1 + i] = v;
  }
}

extern "C" void kernel_launch(void* const* d_in, const int* in_sizes, int n_in,
                              void* d_out, int out_size, void* d_ws, size_t ws_size,
                              hipStream_t stream) {
  const float* preds  = (const float*)d_in[0];
  const float* emb    = (const float*)d_in[1];
  const int*   wsss   = (const int*)d_in[2];
  const int*   fsss   = (const int*)d_in[3];
  const float* memory = (const float*)d_in[4];
  float* out = (float*)d_out;
  char* ws = (char*)d_ws;
  int* hdr = (int*)ws;
  int* easy_idx = (int*)(ws + OFF_EASY);
  int* hard_idx = (int*)(ws + OFF_HARD);
  float* per_anchor = (float*)(ws + OFF_PERA);
  unsigned char* flags1 = (unsigned char*)(ws + OFF_FLAGS1);
  unsigned char* flags2 = (unsigned char*)(ws + OFF_FLAGS2);
  float* anchors = (float*)(ws + OFF_ANCH);
  float* sims = (float*)(ws + OFF_SIMS);

  hipLaunchKernelGGL(k_init,    dim3(1),   dim3(64),  0, stream, hdr);
  hipLaunchKernelGGL(k_prep,    dim3(512), dim3(256), 0, stream, wsss, fsss, flags1, hdr);
  hipLaunchKernelGGL(k_flags,   dim3(512), dim3(256), 0, stream, preds, flags1, flags2, hdr);
  hipLaunchKernelGGL(k_pick,    dim3(1),   dim3(64),  0, stream, flags2, hdr, easy_idx, hard_idx);
  hipLaunchKernelGGL(k_anchors, dim3(256), dim3(64),  0, stream, emb, hdr, easy_idx, hard_idx, anchors);

  // Anchor-chunked sims+topk so the 199x20000 fp32 sims matrix never exceeds ws_size.
  long long avail = (long long)ws_size - (long long)OFF_SIMS;
  int chunkA = (avail > 0) ? (int)(avail / 80000LL) : 1;   // 20000*4 bytes per anchor row
  if (chunkA > A_TOT) chunkA = A_TOT;
  if (chunkA < 1) chunkA = 1;
  for (int aoff = 0; aoff < A_TOT; aoff += chunkA) {
    int acount = (A_TOT - aoff < chunkA) ? (A_TOT - aoff) : chunkA;
    dim3 gs(313, (acount + 63) / 64);
    hipLaunchKernelGGL(k_sims, gs, dim3(256), 0, stream, anchors, memory, sims, aoff, acount);
    hipLaunchKernelGGL(k_topk, dim3(acount), dim3(1024), 0, stream, sims, hdr, per_anchor, aoff, acount);
  }

  hipLaunchKernelGGL(k_loss,    dim3(1),    dim3(256), 0, stream, per_anchor, hdr, out);
  hipLaunchKernelGGL(k_writemem,dim3(2500), dim3(256), 0, stream, memory, anchors, hdr, out);
}